// Round 5
// baseline (783.566 us; speedup 1.0000x reference)
//
#include <hip/hip_runtime.h>

// ALSH masked linear: out[B,N] = x @ (W * mask)^T, mask from bucket match.
// B=2048, D=2048, N=32768, M_AUG=5, TABLE=64, R=4.0, U=0.83.
// Mask is ~all-N -> dense bf16 GEMM.
// R6: - gemm: 256x256/8-wave (1 block/CU, 22% occ, MfmaUtil 42%, conflicts 0)
//       -> 128x128/4-wave 8-phase, 64 KiB LDS => 2 blocks/CU. The vmcnt stall
//       (tile staged ~450cy before use vs ~900cy HBM latency) is structural
//       with a 2-parity ring; cover it with a second independent block (TLP).
//     - dispatch trim: 0 memsets in Path A (colsum -> written partials,
//       maxred -> single-block direct write, flags written non-atomically
//       per mask-block, count/list Path-B-only). 11 dispatches -> 7.
//     - 3-bit LDS swizzle kept verbatim (R5: bank conflicts 2.5e7 -> 0).

#define D_DIM 2048
#define N_ROWS 32768
#define B_ROWS 2048
#define M_AUG_C 5
#define TBL 64
#define RBIN 4.0
#define USC 0.83

typedef short bf16x8 __attribute__((ext_vector_type(8)));
typedef float f32x4 __attribute__((ext_vector_type(4)));

// ---- workspace layout (bytes) ----
#define WS_ROWSUMSQ 0                       // double[N]      256 KB
#define WS_ROWDOTA  262144                  // double[N]      256 KB
#define WS_PARTIAL  524288                  // double[16*D]   256 KB
#define WS_MAXSS    786432                  // double
#define WS_QBUCKET  786440                  // int
#define WS_COUNT    786444                  // int
#define WS_LIST     786448                  // int[N]         128 KB
#define WS_MASKF    917520                  // float[N]       128 KB
#define WS_FLAGS    1048592                 // int[256]       1 KB
#define WS_XB       1114112                 // bf16[B*D]      8 MB
#define WS_WB       9502720                 // bf16[N*D]      128 MB
#define WS_A_NEED   143720448ull            // end of WB

__device__ __forceinline__ unsigned short f2bf(float f) {
    unsigned int u = __builtin_bit_cast(unsigned int, f);
    u += 0x7fffu + ((u >> 16) & 1u);   // round-to-nearest-even
    return (unsigned short)(u >> 16);
}

typedef const __attribute__((address_space(1))) unsigned int* as1_u32p;
typedef __attribute__((address_space(3))) unsigned int* as3_u32p;

__device__ __forceinline__ void gload16(const unsigned short* g, unsigned short* l) {
    __builtin_amdgcn_global_load_lds((as1_u32p)(const void*)g, (as3_u32p)(void*)l,
                                     16, 0, 0);
}

// ---- Kernel A: per-row sum(W^2), dot(W_row, a[:D]) (fp64), bf16(W) emit.
// Block-per-row streaming (R5). ----
__global__ void rowstats_kernel(const float* __restrict__ W,
                                const float* __restrict__ a,
                                double* __restrict__ rowSumSq,
                                double* __restrict__ rowDotA,
                                unsigned short* __restrict__ wb) {
    int row = blockIdx.x;
    int tid = threadIdx.x;
    int col = tid * 8;
    const float* wr = W + (size_t)row * D_DIM + col;
    float4 v0 = *(const float4*)(wr);
    float4 v1 = *(const float4*)(wr + 4);
    float4 a0 = *(const float4*)(a + col);
    float4 a1 = *(const float4*)(a + col + 4);
    if (wb) {
        ushort4 p0, p1;
        p0.x = f2bf(v0.x); p0.y = f2bf(v0.y); p0.z = f2bf(v0.z); p0.w = f2bf(v0.w);
        p1.x = f2bf(v1.x); p1.y = f2bf(v1.y); p1.z = f2bf(v1.z); p1.w = f2bf(v1.w);
        unsigned short* wo = wb + (size_t)row * D_DIM + col;
        *(ushort4*)(wo)     = p0;
        *(ushort4*)(wo + 4) = p1;
    }
    double ss = (double)v0.x * v0.x + (double)v0.y * v0.y + (double)v0.z * v0.z + (double)v0.w * v0.w
              + (double)v1.x * v1.x + (double)v1.y * v1.y + (double)v1.z * v1.z + (double)v1.w * v1.w;
    double da = (double)v0.x * a0.x + (double)v0.y * a0.y + (double)v0.z * a0.z + (double)v0.w * a0.w
              + (double)v1.x * a1.x + (double)v1.y * a1.y + (double)v1.z * a1.z + (double)v1.w * a1.w;
    for (int off = 32; off > 0; off >>= 1) {
        ss += __shfl_down(ss, off);
        da += __shfl_down(da, off);
    }
    __shared__ double sss[4], sda[4];
    int wave = tid >> 6, lane = tid & 63;
    if (lane == 0) { sss[wave] = ss; sda[wave] = da; }
    __syncthreads();
    if (tid == 0) {
        rowSumSq[row] = sss[0] + sss[1] + sss[2] + sss[3];
        rowDotA[row]  = sda[0] + sda[1] + sda[2] + sda[3];
    }
}

// ---- Kernel B: max over rowSumSq, single block, direct write (no memset,
// no atomic). 1024 threads x 32 elems. ----
__global__ void maxred_kernel(const double* __restrict__ rowSumSq,
                              double* __restrict__ maxOut) {
    __shared__ double sm[1024];
    double m = 0.0;
    for (int i = threadIdx.x; i < N_ROWS; i += 1024) m = fmax(m, rowSumSq[i]);
    sm[threadIdx.x] = m;
    __syncthreads();
    for (int s = 512; s > 0; s >>= 1) {
        if (threadIdx.x < s) sm[threadIdx.x] = fmax(sm[threadIdx.x], sm[threadIdx.x + s]);
        __syncthreads();
    }
    if (threadIdx.x == 0) *maxOut = sm[0];
}

// ---- Kernel C1: partial column sums of x (written, no memset needed) ----
__global__ void colsum_kernel(const float* __restrict__ x,
                              double* __restrict__ partial) {
    int col   = blockIdx.x * 256 + threadIdx.x;
    int chunk = blockIdx.y;
    const float* xp = x + (size_t)chunk * 128 * D_DIM + col;
    double s = 0.0;
#pragma unroll 8
    for (int b = 0; b < 128; ++b) s += (double)xp[(size_t)b * D_DIM];
    partial[(size_t)chunk * D_DIM + col] = s;
}

// ---- Kernel C2: finish column sums, compute query bucket ----
__global__ void qhash_kernel(const double* __restrict__ partial,
                             const float* __restrict__ a,
                             int* __restrict__ qBucket) {
    __shared__ double s_ssq[256], s_dta[256];
    int tid = threadIdx.x;
    double ssq = 0.0, dta = 0.0;
    for (int c = tid; c < D_DIM; c += 256) {
        double cs = 0.0;
#pragma unroll
        for (int k = 0; k < 16; ++k) cs += partial[(size_t)k * D_DIM + c];
        ssq += cs * cs;
        dta += cs * (double)a[c];
    }
    s_ssq[tid] = ssq; s_dta[tid] = dta;
    __syncthreads();
    for (int s = 128; s > 0; s >>= 1) {
        if (tid < s) { s_ssq[tid] += s_ssq[tid + s]; s_dta[tid] += s_dta[tid + s]; }
        __syncthreads();
    }
    if (tid == 0) {
        double dq = s_dta[0] / sqrt(s_ssq[0]);
        double aug = 0.0;
        for (int i = 0; i < M_AUG_C; ++i) aug += 0.5 * (double)a[D_DIM + i];
        double h = floor((dq + aug) / RBIN);
        double m = fmod(h, (double)TBL);
        if (m < 0.0) m += (double)TBL;
        *qBucket = (int)m;
    }
}

// ---- Kernel D: row buckets vs query; mask float + non-atomic flags.
// count/list only for Path B (pass nullptr in Path A). ----
__global__ void mask_kernel(const double* __restrict__ rowSumSq,
                            const double* __restrict__ rowDotA,
                            const double* __restrict__ maxSS,
                            const int* __restrict__ qBucket,
                            const float* __restrict__ a,
                            int* __restrict__ count,
                            int* __restrict__ list,
                            float* __restrict__ maskF,
                            int* __restrict__ flags) {
    int n = blockIdx.x * 256 + threadIdx.x;
    double s  = USC / sqrt(*maxSS);
    double n2 = s * s * rowSumSq[n];
    double acc = s * rowDotA[n];
    double p = n2;
#pragma unroll
    for (int i = 0; i < M_AUG_C; ++i) {    // powers n2^(2^i), successive squaring
        acc += p * (double)a[D_DIM + i];
        p = p * p;
    }
    double h = floor(acc / RBIN);
    double m = fmod(h, (double)TBL);
    if (m < 0.0) m += (double)TBL;
    bool active = ((int)m == *qBucket);
    maskF[n] = active ? 1.f : 0.f;

    __shared__ int f2[2];
    if (threadIdx.x < 2) f2[threadIdx.x] = 0;
    __syncthreads();
    if (active) f2[threadIdx.x >> 7] = 1;   // benign race, same value
    __syncthreads();
    if (threadIdx.x < 2) flags[blockIdx.x * 2 + threadIdx.x] = f2[threadIdx.x];

    if (count && active) {
        int pos = atomicAdd(count, 1);
        list[pos] = n;
    }
}

// ---- Kernel E2: x -> bf16 ----
__global__ void convx_kernel(const float* __restrict__ x,
                             unsigned short* __restrict__ xb) {
    size_t e = ((size_t)blockIdx.x * 256 + threadIdx.x) * 8;
    float4 v0 = *(const float4*)(x + e);
    float4 v1 = *(const float4*)(x + e + 4);
    ushort4 p0, p1;
    p0.x = f2bf(v0.x); p0.y = f2bf(v0.y); p0.z = f2bf(v0.z); p0.w = f2bf(v0.w);
    p1.x = f2bf(v1.x); p1.y = f2bf(v1.y); p1.z = f2bf(v1.z); p1.w = f2bf(v1.w);
    *(ushort4*)(xb + e)     = p0;
    *(ushort4*)(xb + e + 4) = p1;
}

// ======== Kernel F-A: 128x128 8-phase bf16 GEMM, 2 blocks/CU ========
// 4 waves (2M x 2N), wave tile 64x64, BK=64, two K-tiles per 8-phase iter.
// LDS: [parity][op][128 rows x 64 cols bf16] = 64 KiB -> 2 blocks/CU; when
// one block drains vmcnt, the other's waves feed the MFMA pipe.
// 3-bit swizzle as R5: logical k-byte kc of row r at physical kc ^ ((r&7)<<4);
// linear LDS dest (global_load_lds) + pre-swizzled global src; XOR on ds_read.
// Staging: tile t1 (parity1) at ph0/ph1 (A then B), consumed ph4-7 (VM0 at ph3);
//          tile u0 (parity0) at ph4/ph5, consumed next-iter ph0-3 (VM0 at ph7).

#define BAR() do { asm volatile("" ::: "memory"); \
                   __builtin_amdgcn_s_barrier(); \
                   asm volatile("" ::: "memory"); } while (0)
#define LGKM0() do { asm volatile("s_waitcnt lgkmcnt(0)" ::: "memory"); \
                     __builtin_amdgcn_sched_barrier(0); } while (0)
#define VM0() asm volatile("s_waitcnt vmcnt(0)" ::: "memory")
#define VM8() asm volatile("s_waitcnt vmcnt(8)" ::: "memory")

// stage call C (0..3) of op-tile (128x64): covers rows C*32..C*32+32
#define STAGE_A2(P, T, C) \
    gload16(xg0 + (size_t)(C) * 32 * D_DIM + (size_t)(T) * 64, \
            &lds[P][0][(C) * 2048 + wid * 512])
#define STAGE_B2(P, T, C) \
    gload16(wg0 + (size_t)(C) * 32 * D_DIM + (size_t)(T) * 64, \
            &lds[P][1][(C) * 2048 + wid * 512])

#define READ_A2(P, MH) do { _Pragma("unroll") \
    for (int m = 0; m < 2; ++m) { \
        aF[m][0] = *(const bf16x8*)(aB##P + ((MH)*2 + m) * 1024 + kOff0); \
        aF[m][1] = *(const bf16x8*)(aB##P + ((MH)*2 + m) * 1024 + kOff1); } } while (0)

#define READ_B2(P, NH) do { _Pragma("unroll") \
    for (int n = 0; n < 2; ++n) { \
        bF[(NH)*2 + n][0] = *(const bf16x8*)(bB##P + ((NH)*2 + n) * 1024 + kOff0); \
        bF[(NH)*2 + n][1] = *(const bf16x8*)(bB##P + ((NH)*2 + n) * 1024 + kOff1); } } while (0)

#define MFMA_Q2(MH, NH) do { _Pragma("unroll") \
    for (int m = 0; m < 2; ++m) { _Pragma("unroll") \
    for (int n = 0; n < 2; ++n) { _Pragma("unroll") \
    for (int kb = 0; kb < 2; ++kb) { \
        acc[(MH)*2 + m][(NH)*2 + n] = __builtin_amdgcn_mfma_f32_16x16x32_bf16( \
            aF[m][kb], bF[(NH)*2 + n][kb], acc[(MH)*2 + m][(NH)*2 + n], 0, 0, 0); \
    } } } } while (0)

__launch_bounds__(256, 2)
__global__ void gemm_128(const unsigned short* __restrict__ xb,
                         const unsigned short* __restrict__ wb,
                         const int* __restrict__ flags,
                         const float* __restrict__ maskF,
                         float* __restrict__ out) {
    int bRow0 = blockIdx.x * 128;
    int nRow0 = blockIdx.y * 128;
    int tid = threadIdx.x;

    if (flags[blockIdx.y] == 0) {
#pragma unroll
        for (int i = 0; i < 16; ++i) {
            int idx = tid + i * 256;
            int r = idx >> 5, c = idx & 31;
            *(float4*)(out + (size_t)(bRow0 + r) * N_ROWS + nRow0 + c * 4) =
                float4{0.f, 0.f, 0.f, 0.f};
        }
        return;
    }

    __shared__ __align__(16) unsigned short lds[2][2][128 * 64];  // 64 KiB

    int wid  = tid >> 6, lane = tid & 63;
    int l16  = lane & 15, quad = lane >> 4;
    int wm   = wid >> 1,  wn   = wid & 1;

    // staging geometry: call C, wave wid, lane l -> LDS linear row
    //   C*32 + wid*8 + (l>>3), col slot (l&7)*16B. Source pre-swizzled:
    //   logical kc = ((l&7)*16) ^ ((row&7)<<4), row&7 = l>>3.
    int srow  = wid * 8 + (lane >> 3);
    int gcolb = (((lane & 7) ^ (lane >> 3)) * 16);   // bytes
    const unsigned short* xg0 = xb + (size_t)(bRow0 + srow) * D_DIM + (gcolb >> 1);
    const unsigned short* wg0 = wb + (size_t)(nRow0 + srow) * D_DIM + (gcolb >> 1);

    // fragment reads: row&7 = l16&7; physical koff = kc ^ ((l16&7)<<4), per kb.
    const int kOff0 = (((quad * 16)      ^ ((l16 & 7) << 4)) >> 1);   // shorts
    const int kOff1 = (((quad * 16 + 64) ^ ((l16 & 7) << 4)) >> 1);

    const unsigned short* aB0 = &lds[0][0][0] + (wm * 64 + l16) * 64;
    const unsigned short* aB1 = &lds[1][0][0] + (wm * 64 + l16) * 64;
    const unsigned short* bB0 = &lds[0][1][0] + (wn * 64 + l16) * 64;
    const unsigned short* bB1 = &lds[1][1][0] + (wn * 64 + l16) * 64;

    f32x4 acc[4][4];
#pragma unroll
    for (int mi = 0; mi < 4; ++mi)
#pragma unroll
        for (int nf = 0; nf < 4; ++nf)
            acc[mi][nf] = (f32x4){0.f, 0.f, 0.f, 0.f};

    bf16x8 aF[2][2], bF[4][2];

    // ---- prologue: stage tile 0 (parity 0) and tile 1 (parity 1) ----
    STAGE_A2(0, 0, 0); STAGE_A2(0, 0, 1); STAGE_A2(0, 0, 2); STAGE_A2(0, 0, 3);
    STAGE_B2(0, 0, 0); STAGE_B2(0, 0, 1); STAGE_B2(0, 0, 2); STAGE_B2(0, 0, 3);
    STAGE_A2(1, 1, 0); STAGE_A2(1, 1, 1); STAGE_A2(1, 1, 2); STAGE_A2(1, 1, 3);
    STAGE_B2(1, 1, 0); STAGE_B2(1, 1, 1); STAGE_B2(1, 1, 2); STAGE_B2(1, 1, 3);
    VM8();           // drain tile 0 (oldest 8), keep tile 1 in flight
    BAR();

    // ---- main: 16 iterations x (2 K-tiles, 8 phases). 32 K-tiles total. ----
#pragma unroll 1
    for (int i = 0; i < 16; ++i) {
        const int t1 = 2 * i + 1;
        const int u0 = 2 * i + 2;

        // ph0: parity0 Q(0,0); stage A(t1) -> parity1 (i>0; i==0 pre-staged)
        READ_A2(0, 0); READ_B2(0, 0);
        if (i > 0) { STAGE_A2(1, t1, 0); STAGE_A2(1, t1, 1);
                     STAGE_A2(1, t1, 2); STAGE_A2(1, t1, 3); }
        BAR(); LGKM0();
        __builtin_amdgcn_s_setprio(1); MFMA_Q2(0, 0); __builtin_amdgcn_s_setprio(0);
        BAR();
        // ph1: Q(0,1); stage B(t1)
        READ_B2(0, 1);
        if (i > 0) { STAGE_B2(1, t1, 0); STAGE_B2(1, t1, 1);
                     STAGE_B2(1, t1, 2); STAGE_B2(1, t1, 3); }
        BAR(); LGKM0();
        __builtin_amdgcn_s_setprio(1); MFMA_Q2(0, 1); __builtin_amdgcn_s_setprio(0);
        BAR();
        // ph2: Q(1,1)
        READ_A2(0, 1);
        BAR(); LGKM0();
        __builtin_amdgcn_s_setprio(1); MFMA_Q2(1, 1); __builtin_amdgcn_s_setprio(0);
        BAR();
        // ph3: Q(1,0); t1 must be resident for ph4
        BAR(); LGKM0();
        __builtin_amdgcn_s_setprio(1); MFMA_Q2(1, 0); __builtin_amdgcn_s_setprio(0);
        VM0();
        BAR();
        // ph4: parity1 Q(0,0); stage A(u0) -> parity0 (i<15)
        READ_A2(1, 0); READ_B2(1, 0);
        if (i < 15) { STAGE_A2(0, u0, 0); STAGE_A2(0, u0, 1);
                      STAGE_A2(0, u0, 2); STAGE_A2(0, u0, 3); }
        BAR(); LGKM0();
        __builtin_amdgcn_s_setprio(1); MFMA_Q2(0, 0); __builtin_amdgcn_s_setprio(0);
        BAR();
        // ph5: Q(0,1); stage B(u0)
        READ_B2(1, 1);
        if (i < 15) { STAGE_B2(0, u0, 0); STAGE_B2(0, u0, 1);
                      STAGE_B2(0, u0, 2); STAGE_B2(0, u0, 3); }
        BAR(); LGKM0();
        __builtin_amdgcn_s_setprio(1); MFMA_Q2(0, 1); __builtin_amdgcn_s_setprio(0);
        BAR();
        // ph6: Q(1,1)
        READ_A2(1, 1);
        BAR(); LGKM0();
        __builtin_amdgcn_s_setprio(1); MFMA_Q2(1, 1); __builtin_amdgcn_s_setprio(0);
        BAR();
        // ph7: Q(1,0); u0 must be resident for next ph0
        BAR(); LGKM0();
        __builtin_amdgcn_s_setprio(1); MFMA_Q2(1, 0); __builtin_amdgcn_s_setprio(0);
        VM0();
        BAR();
    }

    // epilogue: C/D layout col=l16 (n), row=quad*4+reg (b); scale by mask[col]
#pragma unroll
    for (int nf = 0; nf < 4; ++nf) {
        int col = nRow0 + wn * 64 + nf * 16 + l16;
        float mv = maskF[col];
#pragma unroll
        for (int mi = 0; mi < 4; ++mi) {
            int rbase = bRow0 + wm * 64 + mi * 16 + quad * 4;
#pragma unroll
            for (int r = 0; r < 4; ++r)
                out[(size_t)(rbase + r) * N_ROWS + col] = acc[mi][nf][r] * mv;
        }
    }
}

// ---- Kernel F-B (fallback, small ws): compacted-list GEMM from R1 ----
__launch_bounds__(256, 2)
__global__ void gemm_kernel(const float* __restrict__ x,
                            const float* __restrict__ W,
                            const int* __restrict__ count,
                            const int* __restrict__ list,
                            float* __restrict__ out) {
    int cnt = *count;
    int jBase = blockIdx.y * 64;
    if (jBase >= cnt) return;
    int bRow0 = blockIdx.x * 128;

    __shared__ short xT[128 * 80];
    __shared__ short wT[64 * 80];

    int tid  = threadIdx.x;
    int wave = tid >> 6, lane = tid & 63;
    int quad = lane >> 4, l16 = lane & 15;

    int wrow_ids[4];
#pragma unroll
    for (int i = 0; i < 4; ++i) {
        int idx = tid + i * 256;
        int j = jBase + (idx >> 4);
        wrow_ids[i] = list[j < cnt ? j : (cnt - 1)];
    }

    f32x4 acc[2][4];
#pragma unroll
    for (int mi = 0; mi < 2; ++mi)
#pragma unroll
        for (int nf = 0; nf < 4; ++nf)
            acc[mi][nf] = (f32x4){0.f, 0.f, 0.f, 0.f};

    for (int k0 = 0; k0 < D_DIM; k0 += 64) {
        __syncthreads();
#pragma unroll
        for (int i = 0; i < 8; ++i) {
            int idx = tid + i * 256;
            int r = idx >> 4, kq = idx & 15;
            float4 v = *(const float4*)(x + (size_t)(bRow0 + r) * D_DIM + k0 + kq * 4);
            ushort4 b;
            b.x = f2bf(v.x); b.y = f2bf(v.y); b.z = f2bf(v.z); b.w = f2bf(v.w);
            *(ushort4*)(&xT[r * 80 + kq * 4]) = b;
        }
#pragma unroll
        for (int i = 0; i < 4; ++i) {
            int idx = tid + i * 256;
            int r = idx >> 4, kq = idx & 15;
            float4 v = *(const float4*)(W + (size_t)wrow_ids[i] * D_DIM + k0 + kq * 4);
            ushort4 b;
            b.x = f2bf(v.x); b.y = f2bf(v.y); b.z = f2bf(v.z); b.w = f2bf(v.w);
            *(ushort4*)(&wT[r * 80 + kq * 4]) = b;
        }
        __syncthreads();
#pragma unroll
        for (int kk = 0; kk < 64; kk += 32) {
            bf16x8 a0 = *(const bf16x8*)(&xT[(wave * 32 + l16) * 80 + kk + quad * 8]);
            bf16x8 a1 = *(const bf16x8*)(&xT[(wave * 32 + 16 + l16) * 80 + kk + quad * 8]);
#pragma unroll
            for (int nf = 0; nf < 4; ++nf) {
                bf16x8 bv = *(const bf16x8*)(&wT[(nf * 16 + l16) * 80 + kk + quad * 8]);
                acc[0][nf] = __builtin_amdgcn_mfma_f32_16x16x32_bf16(a0, bv, acc[0][nf], 0, 0, 0);
                acc[1][nf] = __builtin_amdgcn_mfma_f32_16x16x32_bf16(a1, bv, acc[1][nf], 0, 0, 0);
            }
        }
    }

#pragma unroll
    for (int nf = 0; nf < 4; ++nf) {
        int j = jBase + nf * 16 + l16;
        if (j < cnt) {
            int col = list[j];
#pragma unroll
            for (int mi = 0; mi < 2; ++mi) {
                int rbase = bRow0 + wave * 32 + mi * 16 + quad * 4;
#pragma unroll
                for (int r = 0; r < 4; ++r)
                    out[(size_t)(rbase + r) * N_ROWS + col] = acc[mi][nf][r];
            }
        }
    }
}

extern "C" void kernel_launch(void* const* d_in, const int* in_sizes, int n_in,
                              void* d_out, int out_size, void* d_ws, size_t ws_size,
                              hipStream_t stream) {
    const float* x = (const float*)d_in[0];
    const float* W = (const float*)d_in[1];
    const float* a = (const float*)d_in[2];
    float* out = (float*)d_out;
    char* ws = (char*)d_ws;

    double* rowSumSq = (double*)(ws + WS_ROWSUMSQ);
    double* rowDotA  = (double*)(ws + WS_ROWDOTA);
    double* partial  = (double*)(ws + WS_PARTIAL);
    double* maxSS    = (double*)(ws + WS_MAXSS);
    int*    qBucket  = (int*)(ws + WS_QBUCKET);
    int*    count    = (int*)(ws + WS_COUNT);
    int*    list     = (int*)(ws + WS_LIST);
    float*  maskF    = (float*)(ws + WS_MASKF);
    int*    flags    = (int*)(ws + WS_FLAGS);
    unsigned short* xb = (unsigned short*)(ws + WS_XB);
    unsigned short* wb = (unsigned short*)(ws + WS_WB);

    bool pathA = (ws_size >= WS_A_NEED);

    // Path A: zero memsets. Path B needs count + out zeroed.
    if (!pathA) {
        hipMemsetAsync(count, 0, sizeof(int), stream);
        hipMemsetAsync(out, 0, (size_t)out_size * sizeof(float), stream);
    }

    rowstats_kernel<<<N_ROWS, 256, 0, stream>>>(
        W, a, rowSumSq, rowDotA, pathA ? wb : (unsigned short*)0);
    maxred_kernel<<<1, 1024, 0, stream>>>(rowSumSq, maxSS);
    colsum_kernel<<<dim3(D_DIM / 256, 16), 256, 0, stream>>>(x, partial);
    qhash_kernel<<<1, 256, 0, stream>>>(partial, a, qBucket);
    mask_kernel<<<N_ROWS / 256, 256, 0, stream>>>(
        rowSumSq, rowDotA, maxSS, qBucket, a,
        pathA ? (int*)0 : count, pathA ? (int*)0 : list, maskF, flags);

    if (pathA) {
        convx_kernel<<<(B_ROWS * (D_DIM / 8)) / 256, 256, 0, stream>>>(x, xb);
        gemm_128<<<dim3(B_ROWS / 128, N_ROWS / 128), 256, 0, stream>>>(
            xb, wb, flags, maskF, out);
    } else {
        gemm_kernel<<<dim3(B_ROWS / 128, N_ROWS / 64), 256, 0, stream>>>(x, W, count, list, out);
    }
}